// Round 1
// baseline (550.931 us; speedup 1.0000x reference)
//
#include <hip/hip_runtime.h>

// ---------------------------------------------------------------------------
// GCN: x1 = relu(Ahat @ (fts@W1) + b1); x2 = relu(Ahat @ (x1@W2) + b2);
//      out = x2@Wc + bc.  Ahat = D^-1/2 (A + I) D^-1/2, deg from dst column.
// d_out = [out (N*16) | x2 (N*128)] fp32.
// ---------------------------------------------------------------------------

#define IN_DIM 256
#define HID 128
#define OUT_DIM 16

__global__ void k_init_deg(int* deg, int n) {
    int i = blockIdx.x * blockDim.x + threadIdx.x;
    if (i < n) deg[i] = 1;  // self-loop
}

__global__ void k_count(const int* __restrict__ dst, int* deg, int e) {
    int i = blockIdx.x * blockDim.x + threadIdx.x;
    if (i < e) atomicAdd(&deg[dst[i]], 1);
}

__global__ void k_dinv(const int* __restrict__ deg, float* dinv, int n) {
    int i = blockIdx.x * blockDim.x + threadIdx.x;
    if (i < n) dinv[i] = rsqrtf((float)deg[i]);
}

// Single-block scan over counts (deg-1). row_ptr[n] = E at the end.
__global__ void k_scan(const int* __restrict__ deg, int* row_ptr, int* cursor, int n) {
    __shared__ int tmp[1024];
    __shared__ int s_running;
    int tid = threadIdx.x;
    if (tid == 0) s_running = 0;
    __syncthreads();
    for (int base = 0; base < n; base += 1024) {
        int i = base + tid;
        int c = (i < n) ? (deg[i] - 1) : 0;
        tmp[tid] = c;
        __syncthreads();
        for (int off = 1; off < 1024; off <<= 1) {
            int v = (tid >= off) ? tmp[tid - off] : 0;
            __syncthreads();
            tmp[tid] += v;
            __syncthreads();
        }
        int excl = tmp[tid] - c;
        if (i < n) { int r = s_running + excl; row_ptr[i] = r; cursor[i] = r; }
        int total = tmp[1023];
        __syncthreads();
        if (tid == 0) s_running += total;
        __syncthreads();
    }
    if (tid == 0) row_ptr[n] = s_running;
}

__global__ void k_fill(const int* __restrict__ src, const int* __restrict__ dst,
                       int* cursor, int* col, int e) {
    int i = blockIdx.x * blockDim.x + threadIdx.x;
    if (i < e) {
        int p = atomicAdd(&cursor[dst[i]], 1);
        col[p] = src[i];
    }
}

// C[n,128] = A[n,K] @ B[K,128].  64x128 tile/block, 256 threads, 4x8 microtile.
__global__ __launch_bounds__(256) void k_gemm(const float* __restrict__ A,
                                              const float* __restrict__ B,
                                              float* __restrict__ C,
                                              int n, int K) {
    __shared__ float As[64][36];    // pad 36: float4-aligned, 2-way banks (free)
    __shared__ float Bs[32][128];
    int tid  = threadIdx.x;
    int tcol = tid & 15;   // 0..15 -> cols tcol*4 and 64+tcol*4
    int trow = tid >> 4;   // 0..15 -> rows trow*4 .. +3
    int m0 = blockIdx.x * 64;

    float acc[4][8];
    #pragma unroll
    for (int r = 0; r < 4; ++r)
        #pragma unroll
        for (int c = 0; c < 8; ++c) acc[r][c] = 0.f;

    for (int k0 = 0; k0 < K; k0 += 32) {
        // Stage A: 64 rows x 32 k. 4 threads/row, 8 consecutive floats each.
        {
            int r = tid >> 2;
            int c = (tid & 3) * 8;
            int row = m0 + r;
            float4 v0 = make_float4(0, 0, 0, 0), v1 = v0;
            if (row < n) {
                const float* ap = A + (size_t)row * K + k0 + c;
                v0 = *(const float4*)ap;
                v1 = *(const float4*)(ap + 4);
            }
            *(float4*)&As[r][c]     = v0;
            *(float4*)&As[r][c + 4] = v1;
        }
        // Stage B: 32 k-rows x 128 cols. 8 threads/row, 16 floats each.
        {
            int r  = tid >> 3;
            int c0 = (tid & 7) * 16;
            const float* bp = B + (size_t)(k0 + r) * 128 + c0;
            *(float4*)&Bs[r][c0]      = *(const float4*)(bp);
            *(float4*)&Bs[r][c0 + 4]  = *(const float4*)(bp + 4);
            *(float4*)&Bs[r][c0 + 8]  = *(const float4*)(bp + 8);
            *(float4*)&Bs[r][c0 + 12] = *(const float4*)(bp + 12);
        }
        __syncthreads();

        #pragma unroll
        for (int kk = 0; kk < 32; ++kk) {
            float a0 = As[trow * 4 + 0][kk];
            float a1 = As[trow * 4 + 1][kk];
            float a2 = As[trow * 4 + 2][kk];
            float a3 = As[trow * 4 + 3][kk];
            float4 b0 = *(float4*)&Bs[kk][tcol * 4];
            float4 b1 = *(float4*)&Bs[kk][64 + tcol * 4];
            float bb[8] = {b0.x, b0.y, b0.z, b0.w, b1.x, b1.y, b1.z, b1.w};
            float aa[4] = {a0, a1, a2, a3};
            #pragma unroll
            for (int r = 0; r < 4; ++r)
                #pragma unroll
                for (int c = 0; c < 8; ++c)
                    acc[r][c] = fmaf(aa[r], bb[c], acc[r][c]);
        }
        __syncthreads();
    }

    #pragma unroll
    for (int r = 0; r < 4; ++r) {
        int row = m0 + trow * 4 + r;
        if (row < n) {
            float4 v0 = make_float4(acc[r][0], acc[r][1], acc[r][2], acc[r][3]);
            float4 v1 = make_float4(acc[r][4], acc[r][5], acc[r][6], acc[r][7]);
            *(float4*)(C + (size_t)row * 128 + tcol * 4)      = v0;
            *(float4*)(C + (size_t)row * 128 + 64 + tcol * 4) = v1;
        }
    }
}

// One wave per node: h[i] = relu(dinv[i]*(sum_e dinv[src]*xw[src] + dinv[i]*xw[i]) + b)
__global__ __launch_bounds__(256) void k_agg(const float* __restrict__ xw,
                                             const float* __restrict__ dinv,
                                             const int* __restrict__ row_ptr,
                                             const int* __restrict__ col,
                                             const float* __restrict__ bias,
                                             float* __restrict__ h, int n) {
    int wave = threadIdx.x >> 6;
    int lane = threadIdx.x & 63;
    int i = blockIdx.x * 4 + wave;
    if (i >= n) return;
    int e0 = row_ptr[i], e1 = row_ptr[i + 1];
    float ax = 0.f, ay = 0.f;
    for (int e = e0; e < e1; ++e) {
        int s = col[e];
        float w = dinv[s];
        float2 v = *(const float2*)(xw + (size_t)s * 128 + lane * 2);
        ax = fmaf(w, v.x, ax);
        ay = fmaf(w, v.y, ay);
    }
    float di = dinv[i];
    float2 vs = *(const float2*)(xw + (size_t)i * 128 + lane * 2);
    ax = fmaf(di, vs.x, ax);
    ay = fmaf(di, vs.y, ay);
    float2 b = *(const float2*)(bias + lane * 2);
    float ox = fmaf(di, ax, b.x);
    float oy = fmaf(di, ay, b.y);
    ox = fmaxf(ox, 0.f);
    oy = fmaxf(oy, 0.f);
    *(float2*)(h + (size_t)i * 128 + lane * 2) = make_float2(ox, oy);
}

// out[n,16] = h2[n,128] @ Wc[128,16] + bc. 16 rows/block, thread=(row,col).
__global__ __launch_bounds__(256) void k_out(const float* __restrict__ h2,
                                             const float* __restrict__ Wc,
                                             const float* __restrict__ bc,
                                             float* __restrict__ out, int n) {
    __shared__ float Ws[128 * 16];
    __shared__ float bs[16];
    __shared__ float hs[16][128];
    int tid = threadIdx.x;
    for (int t = tid; t < 128 * 16; t += 256) Ws[t] = Wc[t];
    if (tid < 16) bs[tid] = bc[tid];
    int r0 = blockIdx.x * 16;
    {
        int r = tid >> 4;
        int c = (tid & 15) * 8;
        int row = r0 + r;
        if (row < n) {
            const float* hp = h2 + (size_t)row * 128 + c;
            *(float4*)&hs[r][c]     = *(const float4*)hp;
            *(float4*)&hs[r][c + 4] = *(const float4*)(hp + 4);
        }
    }
    __syncthreads();
    int ti = tid >> 4, j = tid & 15;
    float acc = bs[j];
    #pragma unroll 8
    for (int k = 0; k < 128; ++k) acc = fmaf(hs[ti][k], Ws[k * 16 + j], acc);
    int row = r0 + ti;
    if (row < n) out[(size_t)row * 16 + j] = acc;
}

static inline size_t align256(size_t x) { return (x + 255) & ~(size_t)255; }

extern "C" void kernel_launch(void* const* d_in, const int* in_sizes, int n_in,
                              void* d_out, int out_size, void* d_ws, size_t ws_size,
                              hipStream_t stream) {
    const float* fts = (const float*)d_in[0];
    const int*   ei  = (const int*)d_in[1];
    const float* W1  = (const float*)d_in[2];
    const float* b1  = (const float*)d_in[3];
    const float* W2  = (const float*)d_in[4];
    const float* b2  = (const float*)d_in[5];
    const float* Wc  = (const float*)d_in[6];
    const float* bc  = (const float*)d_in[7];

    const int N = in_sizes[0] / IN_DIM;     // 50000
    const int E = in_sizes[1] / 2;          // 800000
    const int* src = ei;
    const int* dst = ei + E;

    // Workspace carve-up
    char* p = (char*)d_ws;
    int* deg      = (int*)p;               p += align256(sizeof(int) * N);
    int* row_ptr  = (int*)p;               p += align256(sizeof(int) * (N + 1));
    int* cursor   = (int*)p;               p += align256(sizeof(int) * N);
    float* dinv   = (float*)p;             p += align256(sizeof(float) * N);
    int* col      = (int*)p;               p += align256(sizeof(int) * E);
    float* xw     = (float*)p;             p += align256(sizeof(float) * (size_t)N * HID);
    float* h1     = (float*)p;             p += align256(sizeof(float) * (size_t)N * HID);

    float* out = (float*)d_out;                   // [N,16]
    float* h2  = (float*)d_out + (size_t)N * 16;  // [N,128] = second tuple output

    const int T = 256;
    dim3 gN((N + T - 1) / T), gE((E + T - 1) / T);

    // Graph structure
    k_init_deg<<<gN, T, 0, stream>>>(deg, N);
    k_count<<<gE, T, 0, stream>>>(dst, deg, E);
    k_dinv<<<gN, T, 0, stream>>>(deg, dinv, N);
    k_scan<<<1, 1024, 0, stream>>>(deg, row_ptr, cursor, N);
    k_fill<<<gE, T, 0, stream>>>(src, dst, cursor, col, E);

    dim3 gGemm((N + 63) / 64);
    dim3 gAgg((N + 3) / 4);

    // Layer 1
    k_gemm<<<gGemm, T, 0, stream>>>(fts, W1, xw, N, IN_DIM);
    k_agg<<<gAgg, T, 0, stream>>>(xw, dinv, row_ptr, col, b1, h1, N);
    // Layer 2
    k_gemm<<<gGemm, T, 0, stream>>>(h1, W2, xw, N, HID);
    k_agg<<<gAgg, T, 0, stream>>>(xw, dinv, row_ptr, col, b2, h2, N);
    // Classifier
    k_out<<<(N + 15) / 16, T, 0, stream>>>(h2, Wc, bc, out, N);
}

// Round 2
// 463.126 us; speedup vs baseline: 1.1896x; 1.1896x over previous
//
#include <hip/hip_runtime.h>

// ---------------------------------------------------------------------------
// GCN: x1 = relu(Ahat @ (fts@W1) + b1); x2 = relu(Ahat @ (x1@W2) + b2);
//      out = x2@Wc + bc.  Ahat = D^-1/2 (A + I) D^-1/2, deg from dst column.
// d_out = [out (N*16) | x2 (N*128)] fp32.
// R2: replaced single-block scan (96us, 0.18% occupancy) with 3-stage
//     hierarchical scan; fused dinv into stage 3.
// ---------------------------------------------------------------------------

#define IN_DIM 256
#define HID 128
#define OUT_DIM 16
#define SCAN_B 256   // threads per scan block; grid = ceil(N/256)

__global__ void k_init_deg(int* deg, int n) {
    int i = blockIdx.x * blockDim.x + threadIdx.x;
    if (i < n) deg[i] = 1;  // self-loop
}

__global__ void k_count(const int* __restrict__ dst, int* deg, int e) {
    int i = blockIdx.x * blockDim.x + threadIdx.x;
    if (i < e) atomicAdd(&deg[dst[i]], 1);
}

// Stage 1: per-block exclusive scan of (deg-1); emit block totals.
__global__ __launch_bounds__(SCAN_B) void k_scan1(const int* __restrict__ deg,
                                                  int* __restrict__ row_ptr,
                                                  int* __restrict__ bsum, int n) {
    __shared__ int tmp[SCAN_B];
    int tid = threadIdx.x;
    int i = blockIdx.x * SCAN_B + tid;
    int c = (i < n) ? (deg[i] - 1) : 0;
    tmp[tid] = c;
    __syncthreads();
    #pragma unroll
    for (int off = 1; off < SCAN_B; off <<= 1) {
        int v = (tid >= off) ? tmp[tid - off] : 0;
        __syncthreads();
        tmp[tid] += v;
        __syncthreads();
    }
    if (i < n) row_ptr[i] = tmp[tid] - c;          // local exclusive
    if (tid == SCAN_B - 1) bsum[blockIdx.x] = tmp[tid];
}

// Stage 2: one block scans the block totals (nb <= SCAN_B) into excl offsets.
__global__ __launch_bounds__(SCAN_B) void k_scan2(int* __restrict__ bsum, int nb) {
    __shared__ int tmp[SCAN_B];
    int tid = threadIdx.x;
    int c = (tid < nb) ? bsum[tid] : 0;
    tmp[tid] = c;
    __syncthreads();
    #pragma unroll
    for (int off = 1; off < SCAN_B; off <<= 1) {
        int v = (tid >= off) ? tmp[tid - off] : 0;
        __syncthreads();
        tmp[tid] += v;
        __syncthreads();
    }
    if (tid < nb) bsum[tid] = tmp[tid] - c;        // exclusive
}

// Stage 3: add block offsets, init cursor, fused dinv; one lane sets row_ptr[n].
__global__ __launch_bounds__(SCAN_B) void k_scan3(int* __restrict__ row_ptr,
                                                  const int* __restrict__ bsum,
                                                  int* __restrict__ cursor,
                                                  const int* __restrict__ deg,
                                                  float* __restrict__ dinv,
                                                  int n, int e) {
    int i = blockIdx.x * SCAN_B + threadIdx.x;
    if (i < n) {
        int r = row_ptr[i] + bsum[blockIdx.x];
        row_ptr[i] = r;
        cursor[i] = r;
        dinv[i] = rsqrtf((float)deg[i]);
    }
    if (i == 0) row_ptr[n] = e;
}

__global__ void k_fill(const int* __restrict__ src, const int* __restrict__ dst,
                       int* cursor, int* col, int e) {
    int i = blockIdx.x * blockDim.x + threadIdx.x;
    if (i < e) {
        int p = atomicAdd(&cursor[dst[i]], 1);
        col[p] = src[i];
    }
}

// C[n,128] = A[n,K] @ B[K,128].  64x128 tile/block, 256 threads, 4x8 microtile.
__global__ __launch_bounds__(256) void k_gemm(const float* __restrict__ A,
                                              const float* __restrict__ B,
                                              float* __restrict__ C,
                                              int n, int K) {
    __shared__ float As[64][36];    // pad 36: float4-aligned, 2-way banks (free)
    __shared__ float Bs[32][128];
    int tid  = threadIdx.x;
    int tcol = tid & 15;   // 0..15 -> cols tcol*4 and 64+tcol*4
    int trow = tid >> 4;   // 0..15 -> rows trow*4 .. +3
    int m0 = blockIdx.x * 64;

    float acc[4][8];
    #pragma unroll
    for (int r = 0; r < 4; ++r)
        #pragma unroll
        for (int c = 0; c < 8; ++c) acc[r][c] = 0.f;

    for (int k0 = 0; k0 < K; k0 += 32) {
        // Stage A: 64 rows x 32 k. 4 threads/row, 8 consecutive floats each.
        {
            int r = tid >> 2;
            int c = (tid & 3) * 8;
            int row = m0 + r;
            float4 v0 = make_float4(0, 0, 0, 0), v1 = v0;
            if (row < n) {
                const float* ap = A + (size_t)row * K + k0 + c;
                v0 = *(const float4*)ap;
                v1 = *(const float4*)(ap + 4);
            }
            *(float4*)&As[r][c]     = v0;
            *(float4*)&As[r][c + 4] = v1;
        }
        // Stage B: 32 k-rows x 128 cols. 8 threads/row, 16 floats each.
        {
            int r  = tid >> 3;
            int c0 = (tid & 7) * 16;
            const float* bp = B + (size_t)(k0 + r) * 128 + c0;
            *(float4*)&Bs[r][c0]      = *(const float4*)(bp);
            *(float4*)&Bs[r][c0 + 4]  = *(const float4*)(bp + 4);
            *(float4*)&Bs[r][c0 + 8]  = *(const float4*)(bp + 8);
            *(float4*)&Bs[r][c0 + 12] = *(const float4*)(bp + 12);
        }
        __syncthreads();

        #pragma unroll
        for (int kk = 0; kk < 32; ++kk) {
            float a0 = As[trow * 4 + 0][kk];
            float a1 = As[trow * 4 + 1][kk];
            float a2 = As[trow * 4 + 2][kk];
            float a3 = As[trow * 4 + 3][kk];
            float4 b0 = *(float4*)&Bs[kk][tcol * 4];
            float4 b1 = *(float4*)&Bs[kk][64 + tcol * 4];
            float bb[8] = {b0.x, b0.y, b0.z, b0.w, b1.x, b1.y, b1.z, b1.w};
            float aa[4] = {a0, a1, a2, a3};
            #pragma unroll
            for (int r = 0; r < 4; ++r)
                #pragma unroll
                for (int c = 0; c < 8; ++c)
                    acc[r][c] = fmaf(aa[r], bb[c], acc[r][c]);
        }
        __syncthreads();
    }

    #pragma unroll
    for (int r = 0; r < 4; ++r) {
        int row = m0 + trow * 4 + r;
        if (row < n) {
            float4 v0 = make_float4(acc[r][0], acc[r][1], acc[r][2], acc[r][3]);
            float4 v1 = make_float4(acc[r][4], acc[r][5], acc[r][6], acc[r][7]);
            *(float4*)(C + (size_t)row * 128 + tcol * 4)      = v0;
            *(float4*)(C + (size_t)row * 128 + 64 + tcol * 4) = v1;
        }
    }
}

// One wave per node: h[i] = relu(dinv[i]*(sum_e dinv[src]*xw[src] + dinv[i]*xw[i]) + b)
__global__ __launch_bounds__(256) void k_agg(const float* __restrict__ xw,
                                             const float* __restrict__ dinv,
                                             const int* __restrict__ row_ptr,
                                             const int* __restrict__ col,
                                             const float* __restrict__ bias,
                                             float* __restrict__ h, int n) {
    int wave = threadIdx.x >> 6;
    int lane = threadIdx.x & 63;
    int i = blockIdx.x * 4 + wave;
    if (i >= n) return;
    int e0 = row_ptr[i], e1 = row_ptr[i + 1];
    float ax = 0.f, ay = 0.f;
    for (int e = e0; e < e1; ++e) {
        int s = col[e];
        float w = dinv[s];
        float2 v = *(const float2*)(xw + (size_t)s * 128 + lane * 2);
        ax = fmaf(w, v.x, ax);
        ay = fmaf(w, v.y, ay);
    }
    float di = dinv[i];
    float2 vs = *(const float2*)(xw + (size_t)i * 128 + lane * 2);
    ax = fmaf(di, vs.x, ax);
    ay = fmaf(di, vs.y, ay);
    float2 b = *(const float2*)(bias + lane * 2);
    float ox = fmaf(di, ax, b.x);
    float oy = fmaf(di, ay, b.y);
    ox = fmaxf(ox, 0.f);
    oy = fmaxf(oy, 0.f);
    *(float2*)(h + (size_t)i * 128 + lane * 2) = make_float2(ox, oy);
}

// out[n,16] = h2[n,128] @ Wc[128,16] + bc. 16 rows/block, thread=(row,col).
__global__ __launch_bounds__(256) void k_out(const float* __restrict__ h2,
                                             const float* __restrict__ Wc,
                                             const float* __restrict__ bc,
                                             float* __restrict__ out, int n) {
    __shared__ float Ws[128 * 16];
    __shared__ float bs[16];
    __shared__ float hs[16][128];
    int tid = threadIdx.x;
    for (int t = tid; t < 128 * 16; t += 256) Ws[t] = Wc[t];
    if (tid < 16) bs[tid] = bc[tid];
    int r0 = blockIdx.x * 16;
    {
        int r = tid >> 4;
        int c = (tid & 15) * 8;
        int row = r0 + r;
        if (row < n) {
            const float* hp = h2 + (size_t)row * 128 + c;
            *(float4*)&hs[r][c]     = *(const float4*)hp;
            *(float4*)&hs[r][c + 4] = *(const float4*)(hp + 4);
        }
    }
    __syncthreads();
    int ti = tid >> 4, j = tid & 15;
    float acc = bs[j];
    #pragma unroll 8
    for (int k = 0; k < 128; ++k) acc = fmaf(hs[ti][k], Ws[k * 16 + j], acc);
    int row = r0 + ti;
    if (row < n) out[(size_t)row * 16 + j] = acc;
}

static inline size_t align256(size_t x) { return (x + 255) & ~(size_t)255; }

extern "C" void kernel_launch(void* const* d_in, const int* in_sizes, int n_in,
                              void* d_out, int out_size, void* d_ws, size_t ws_size,
                              hipStream_t stream) {
    const float* fts = (const float*)d_in[0];
    const int*   ei  = (const int*)d_in[1];
    const float* W1  = (const float*)d_in[2];
    const float* b1  = (const float*)d_in[3];
    const float* W2  = (const float*)d_in[4];
    const float* b2  = (const float*)d_in[5];
    const float* Wc  = (const float*)d_in[6];
    const float* bc  = (const float*)d_in[7];

    const int N = in_sizes[0] / IN_DIM;     // 50000
    const int E = in_sizes[1] / 2;          // 800000
    const int* src = ei;
    const int* dst = ei + E;

    // Workspace carve-up
    char* p = (char*)d_ws;
    int* deg      = (int*)p;               p += align256(sizeof(int) * N);
    int* row_ptr  = (int*)p;               p += align256(sizeof(int) * (N + 1));
    int* cursor   = (int*)p;               p += align256(sizeof(int) * N);
    float* dinv   = (float*)p;             p += align256(sizeof(float) * N);
    int* col      = (int*)p;               p += align256(sizeof(int) * E);
    int* bsum     = (int*)p;               p += align256(sizeof(int) * 512);
    float* xw     = (float*)p;             p += align256(sizeof(float) * (size_t)N * HID);
    float* h1     = (float*)p;             p += align256(sizeof(float) * (size_t)N * HID);

    float* out = (float*)d_out;                   // [N,16]
    float* h2  = (float*)d_out + (size_t)N * 16;  // [N,128] = second tuple output

    const int T = 256;
    dim3 gN((N + T - 1) / T), gE((E + T - 1) / T);
    const int nScanB = (N + SCAN_B - 1) / SCAN_B;   // 196 <= 256

    // Graph structure
    k_init_deg<<<gN, T, 0, stream>>>(deg, N);
    k_count<<<gE, T, 0, stream>>>(dst, deg, E);
    k_scan1<<<nScanB, SCAN_B, 0, stream>>>(deg, row_ptr, bsum, N);
    k_scan2<<<1, SCAN_B, 0, stream>>>(bsum, nScanB);
    k_scan3<<<nScanB, SCAN_B, 0, stream>>>(row_ptr, bsum, cursor, deg, dinv, N, E);
    k_fill<<<gE, T, 0, stream>>>(src, dst, cursor, col, E);

    dim3 gGemm((N + 63) / 64);
    dim3 gAgg((N + 3) / 4);

    // Layer 1
    k_gemm<<<gGemm, T, 0, stream>>>(fts, W1, xw, N, IN_DIM);
    k_agg<<<gAgg, T, 0, stream>>>(xw, dinv, row_ptr, col, b1, h1, N);
    // Layer 2
    k_gemm<<<gGemm, T, 0, stream>>>(h1, W2, xw, N, HID);
    k_agg<<<gAgg, T, 0, stream>>>(xw, dinv, row_ptr, col, b2, h2, N);
    // Classifier
    k_out<<<(N + 15) / 16, T, 0, stream>>>(h2, Wc, bc, out, N);
}

// Round 3
// 377.958 us; speedup vs baseline: 1.4577x; 1.2253x over previous
//
#include <hip/hip_runtime.h>

// ---------------------------------------------------------------------------
// GCN: x1 = relu(Ahat @ (fts@W1) + b1); x2 = relu(Ahat @ (x1@W2) + b2);
//      out = x2@Wc + bc.  Ahat = D^-1/2 (A + I) D^-1/2, deg from dst column.
// d_out = [out (N*16) | x2 (N*128)] fp32.
// R2: 3-stage hierarchical scan (96us -> ~5us).
// R3: k_agg restructure — dinv[src] prescaled in GEMM epilogue (kills the
//     per-edge dependent dinv load), xw stored bf16 (256B/row gather, halves
//     the 187MB/dispatch L2-fill traffic), edge loop unrolled x8 for MLP.
// ---------------------------------------------------------------------------

#define IN_DIM 256
#define HID 128
#define OUT_DIM 16
#define SCAN_B 256

__device__ __forceinline__ unsigned short f2bf(float f) {
    union { float f; unsigned int u; } c; c.f = f;
    unsigned int u = c.u;
    unsigned int r = (u + 0x7fffu + ((u >> 16) & 1u)) >> 16;   // RTNE
    return (unsigned short)r;
}
__device__ __forceinline__ float bf_lo(unsigned int u) {
    union { unsigned int u; float f; } c; c.u = u << 16; return c.f;
}
__device__ __forceinline__ float bf_hi(unsigned int u) {
    union { unsigned int u; float f; } c; c.u = u & 0xffff0000u; return c.f;
}

__global__ void k_init_deg(int* deg, int n) {
    int i = blockIdx.x * blockDim.x + threadIdx.x;
    if (i < n) deg[i] = 1;  // self-loop
}

__global__ void k_count(const int* __restrict__ dst, int* deg, int e) {
    int i = blockIdx.x * blockDim.x + threadIdx.x;
    if (i < e) atomicAdd(&deg[dst[i]], 1);
}

__global__ __launch_bounds__(SCAN_B) void k_scan1(const int* __restrict__ deg,
                                                  int* __restrict__ row_ptr,
                                                  int* __restrict__ bsum, int n) {
    __shared__ int tmp[SCAN_B];
    int tid = threadIdx.x;
    int i = blockIdx.x * SCAN_B + tid;
    int c = (i < n) ? (deg[i] - 1) : 0;
    tmp[tid] = c;
    __syncthreads();
    #pragma unroll
    for (int off = 1; off < SCAN_B; off <<= 1) {
        int v = (tid >= off) ? tmp[tid - off] : 0;
        __syncthreads();
        tmp[tid] += v;
        __syncthreads();
    }
    if (i < n) row_ptr[i] = tmp[tid] - c;
    if (tid == SCAN_B - 1) bsum[blockIdx.x] = tmp[tid];
}

__global__ __launch_bounds__(SCAN_B) void k_scan2(int* __restrict__ bsum, int nb) {
    __shared__ int tmp[SCAN_B];
    int tid = threadIdx.x;
    int c = (tid < nb) ? bsum[tid] : 0;
    tmp[tid] = c;
    __syncthreads();
    #pragma unroll
    for (int off = 1; off < SCAN_B; off <<= 1) {
        int v = (tid >= off) ? tmp[tid - off] : 0;
        __syncthreads();
        tmp[tid] += v;
        __syncthreads();
    }
    if (tid < nb) bsum[tid] = tmp[tid] - c;
}

__global__ __launch_bounds__(SCAN_B) void k_scan3(int* __restrict__ row_ptr,
                                                  const int* __restrict__ bsum,
                                                  int* __restrict__ cursor,
                                                  const int* __restrict__ deg,
                                                  float* __restrict__ dinv,
                                                  int n, int e) {
    int i = blockIdx.x * SCAN_B + threadIdx.x;
    if (i < n) {
        int r = row_ptr[i] + bsum[blockIdx.x];
        row_ptr[i] = r;
        cursor[i] = r;
        dinv[i] = rsqrtf((float)deg[i]);
    }
    if (i == 0) row_ptr[n] = e;
}

__global__ void k_fill(const int* __restrict__ src, const int* __restrict__ dst,
                       int* cursor, int* col, int e) {
    int i = blockIdx.x * blockDim.x + threadIdx.x;
    if (i < e) {
        int p = atomicAdd(&cursor[dst[i]], 1);
        col[p] = src[i];
    }
}

// Cb[n,128](bf16) = dinv[row] * (A[n,K] @ B[K,128]). 64x128 tile, 256 thr.
__global__ __launch_bounds__(256) void k_gemm(const float* __restrict__ A,
                                              const float* __restrict__ B,
                                              unsigned short* __restrict__ Cb,
                                              const float* __restrict__ dinv,
                                              int n, int K) {
    __shared__ float As[64][36];
    __shared__ float Bs[32][128];
    int tid  = threadIdx.x;
    int tcol = tid & 15;
    int trow = tid >> 4;
    int m0 = blockIdx.x * 64;

    float acc[4][8];
    #pragma unroll
    for (int r = 0; r < 4; ++r)
        #pragma unroll
        for (int c = 0; c < 8; ++c) acc[r][c] = 0.f;

    for (int k0 = 0; k0 < K; k0 += 32) {
        {
            int r = tid >> 2;
            int c = (tid & 3) * 8;
            int row = m0 + r;
            float4 v0 = make_float4(0, 0, 0, 0), v1 = v0;
            if (row < n) {
                const float* ap = A + (size_t)row * K + k0 + c;
                v0 = *(const float4*)ap;
                v1 = *(const float4*)(ap + 4);
            }
            *(float4*)&As[r][c]     = v0;
            *(float4*)&As[r][c + 4] = v1;
        }
        {
            int r  = tid >> 3;
            int c0 = (tid & 7) * 16;
            const float* bp = B + (size_t)(k0 + r) * 128 + c0;
            *(float4*)&Bs[r][c0]      = *(const float4*)(bp);
            *(float4*)&Bs[r][c0 + 4]  = *(const float4*)(bp + 4);
            *(float4*)&Bs[r][c0 + 8]  = *(const float4*)(bp + 8);
            *(float4*)&Bs[r][c0 + 12] = *(const float4*)(bp + 12);
        }
        __syncthreads();

        #pragma unroll
        for (int kk = 0; kk < 32; ++kk) {
            float aa[4] = {As[trow * 4 + 0][kk], As[trow * 4 + 1][kk],
                           As[trow * 4 + 2][kk], As[trow * 4 + 3][kk]};
            float4 b0 = *(float4*)&Bs[kk][tcol * 4];
            float4 b1 = *(float4*)&Bs[kk][64 + tcol * 4];
            float bb[8] = {b0.x, b0.y, b0.z, b0.w, b1.x, b1.y, b1.z, b1.w};
            #pragma unroll
            for (int r = 0; r < 4; ++r)
                #pragma unroll
                for (int c = 0; c < 8; ++c)
                    acc[r][c] = fmaf(aa[r], bb[c], acc[r][c]);
        }
        __syncthreads();
    }

    #pragma unroll
    for (int r = 0; r < 4; ++r) {
        int row = m0 + trow * 4 + r;
        if (row < n) {
            float d = dinv[row];
            unsigned int p0 = (unsigned int)f2bf(acc[r][0] * d) |
                              ((unsigned int)f2bf(acc[r][1] * d) << 16);
            unsigned int p1 = (unsigned int)f2bf(acc[r][2] * d) |
                              ((unsigned int)f2bf(acc[r][3] * d) << 16);
            unsigned int p2 = (unsigned int)f2bf(acc[r][4] * d) |
                              ((unsigned int)f2bf(acc[r][5] * d) << 16);
            unsigned int p3 = (unsigned int)f2bf(acc[r][6] * d) |
                              ((unsigned int)f2bf(acc[r][7] * d) << 16);
            unsigned int* o0 = (unsigned int*)(Cb + (size_t)row * 128 + tcol * 4);
            unsigned int* o1 = (unsigned int*)(Cb + (size_t)row * 128 + 64 + tcol * 4);
            o0[0] = p0; o0[1] = p1;
            o1[0] = p2; o1[1] = p3;
        }
    }
}

// One wave per node. xwb rows already scaled by dinv[src].
// h[i] = relu(dinv[i]*(sum_e xwb[col[e]] + xwb[i]) + b)
__global__ __launch_bounds__(256) void k_agg(const unsigned short* __restrict__ xwb,
                                             const float* __restrict__ dinv,
                                             const int* __restrict__ row_ptr,
                                             const int* __restrict__ col,
                                             const float* __restrict__ bias,
                                             float* __restrict__ h, int n) {
    int wave = threadIdx.x >> 6;
    int lane = threadIdx.x & 63;
    int i = blockIdx.x * 4 + wave;
    if (i >= n) return;
    int e0 = row_ptr[i], e1 = row_ptr[i + 1];
    float ax = 0.f, ay = 0.f;
    int e = e0;
    // main: 8 edges in flight
    for (; e + 8 <= e1; e += 8) {
        int s0 = col[e + 0], s1 = col[e + 1], s2 = col[e + 2], s3 = col[e + 3];
        int s4 = col[e + 4], s5 = col[e + 5], s6 = col[e + 6], s7 = col[e + 7];
        unsigned int u0 = *(const unsigned int*)(xwb + (size_t)s0 * 128 + lane * 2);
        unsigned int u1 = *(const unsigned int*)(xwb + (size_t)s1 * 128 + lane * 2);
        unsigned int u2 = *(const unsigned int*)(xwb + (size_t)s2 * 128 + lane * 2);
        unsigned int u3 = *(const unsigned int*)(xwb + (size_t)s3 * 128 + lane * 2);
        unsigned int u4 = *(const unsigned int*)(xwb + (size_t)s4 * 128 + lane * 2);
        unsigned int u5 = *(const unsigned int*)(xwb + (size_t)s5 * 128 + lane * 2);
        unsigned int u6 = *(const unsigned int*)(xwb + (size_t)s6 * 128 + lane * 2);
        unsigned int u7 = *(const unsigned int*)(xwb + (size_t)s7 * 128 + lane * 2);
        ax += bf_lo(u0) + bf_lo(u1) + bf_lo(u2) + bf_lo(u3)
            + bf_lo(u4) + bf_lo(u5) + bf_lo(u6) + bf_lo(u7);
        ay += bf_hi(u0) + bf_hi(u1) + bf_hi(u2) + bf_hi(u3)
            + bf_hi(u4) + bf_hi(u5) + bf_hi(u6) + bf_hi(u7);
    }
    // tail (wave-uniform branches)
    for (; e < e1; ++e) {
        int s = col[e];
        unsigned int u = *(const unsigned int*)(xwb + (size_t)s * 128 + lane * 2);
        ax += bf_lo(u);
        ay += bf_hi(u);
    }
    // self-loop
    {
        unsigned int u = *(const unsigned int*)(xwb + (size_t)i * 128 + lane * 2);
        ax += bf_lo(u);
        ay += bf_hi(u);
    }
    float di = dinv[i];
    float2 b = *(const float2*)(bias + lane * 2);
    float ox = fmaxf(fmaf(di, ax, b.x), 0.f);
    float oy = fmaxf(fmaf(di, ay, b.y), 0.f);
    *(float2*)(h + (size_t)i * 128 + lane * 2) = make_float2(ox, oy);
}

// out[n,16] = h2[n,128] @ Wc[128,16] + bc.
__global__ __launch_bounds__(256) void k_out(const float* __restrict__ h2,
                                             const float* __restrict__ Wc,
                                             const float* __restrict__ bc,
                                             float* __restrict__ out, int n) {
    __shared__ float Ws[128 * 16];
    __shared__ float bs[16];
    __shared__ float hs[16][128];
    int tid = threadIdx.x;
    for (int t = tid; t < 128 * 16; t += 256) Ws[t] = Wc[t];
    if (tid < 16) bs[tid] = bc[tid];
    int r0 = blockIdx.x * 16;
    {
        int r = tid >> 4;
        int c = (tid & 15) * 8;
        int row = r0 + r;
        if (row < n) {
            const float* hp = h2 + (size_t)row * 128 + c;
            *(float4*)&hs[r][c]     = *(const float4*)hp;
            *(float4*)&hs[r][c + 4] = *(const float4*)(hp + 4);
        }
    }
    __syncthreads();
    int ti = tid >> 4, j = tid & 15;
    float acc = bs[j];
    #pragma unroll 8
    for (int k = 0; k < 128; ++k) acc = fmaf(hs[ti][k], Ws[k * 16 + j], acc);
    int row = r0 + ti;
    if (row < n) out[(size_t)row * 16 + j] = acc;
}

static inline size_t align256(size_t x) { return (x + 255) & ~(size_t)255; }

extern "C" void kernel_launch(void* const* d_in, const int* in_sizes, int n_in,
                              void* d_out, int out_size, void* d_ws, size_t ws_size,
                              hipStream_t stream) {
    const float* fts = (const float*)d_in[0];
    const int*   ei  = (const int*)d_in[1];
    const float* W1  = (const float*)d_in[2];
    const float* b1  = (const float*)d_in[3];
    const float* W2  = (const float*)d_in[4];
    const float* b2  = (const float*)d_in[5];
    const float* Wc  = (const float*)d_in[6];
    const float* bc  = (const float*)d_in[7];

    const int N = in_sizes[0] / IN_DIM;     // 50000
    const int E = in_sizes[1] / 2;          // 800000
    const int* src = ei;
    const int* dst = ei + E;

    char* p = (char*)d_ws;
    int* deg      = (int*)p;               p += align256(sizeof(int) * N);
    int* row_ptr  = (int*)p;               p += align256(sizeof(int) * (N + 1));
    int* cursor   = (int*)p;               p += align256(sizeof(int) * N);
    float* dinv   = (float*)p;             p += align256(sizeof(float) * N);
    int* col      = (int*)p;               p += align256(sizeof(int) * E);
    int* bsum     = (int*)p;               p += align256(sizeof(int) * 512);
    unsigned short* xwb = (unsigned short*)p;  p += align256(sizeof(unsigned short) * (size_t)N * HID);
    float* h1     = (float*)p;             p += align256(sizeof(float) * (size_t)N * HID);

    float* out = (float*)d_out;                   // [N,16]
    float* h2  = (float*)d_out + (size_t)N * 16;  // [N,128]

    const int T = 256;
    dim3 gN((N + T - 1) / T), gE((E + T - 1) / T);
    const int nScanB = (N + SCAN_B - 1) / SCAN_B;

    k_init_deg<<<gN, T, 0, stream>>>(deg, N);
    k_count<<<gE, T, 0, stream>>>(dst, deg, E);
    k_scan1<<<nScanB, SCAN_B, 0, stream>>>(deg, row_ptr, bsum, N);
    k_scan2<<<1, SCAN_B, 0, stream>>>(bsum, nScanB);
    k_scan3<<<nScanB, SCAN_B, 0, stream>>>(row_ptr, bsum, cursor, deg, dinv, N, E);
    k_fill<<<gE, T, 0, stream>>>(src, dst, cursor, col, E);

    dim3 gGemm((N + 63) / 64);
    dim3 gAgg((N + 3) / 4);

    // Layer 1
    k_gemm<<<gGemm, T, 0, stream>>>(fts, W1, xwb, dinv, N, IN_DIM);
    k_agg<<<gAgg, T, 0, stream>>>(xwb, dinv, row_ptr, col, b1, h1, N);
    // Layer 2
    k_gemm<<<gGemm, T, 0, stream>>>(h1, W2, xwb, dinv, N, HID);
    k_agg<<<gAgg, T, 0, stream>>>(xwb, dinv, row_ptr, col, b2, h2, N);
    // Classifier
    k_out<<<(N + 15) / 16, T, 0, stream>>>(h2, Wc, bc, out, N);
}

// Round 4
// 329.947 us; speedup vs baseline: 1.6698x; 1.1455x over previous
//
#include <hip/hip_runtime.h>

// ---------------------------------------------------------------------------
// GCN: x1 = relu(Ahat @ (fts@W1) + b1); x2 = relu(Ahat @ (x1@W2) + b2);
//      out = x2@Wc + bc.  Ahat = D^-1/2 (A + I) D^-1/2.
// d_out = [out (N*16) | x2 (N*128)] fp32.
// R2: hierarchical scan. R3: bf16 gather + dinv prescale + x8 unroll.
// R4: GEMMs -> mfma_f32_16x16x32_f16, zero LDS. B pre-swizzled to fragment
//     layout; intermediates fp16; D stored in pi-permuted column order
//     (pi(p) = (p&7)*16 + (p>>3)) so epilogue stores are contiguous 16B.
//     Biases pre-permuted; W2 swizzle composes pi on its K dim; layer-2 agg
//     un-permutes on the fp32 h2 write.
// ---------------------------------------------------------------------------

#define IN_DIM 256
#define HID 128
#define OUT_DIM 16
#define SCAN_B 256

typedef _Float16 half8  __attribute__((ext_vector_type(8)));
typedef _Float16 half2v __attribute__((ext_vector_type(2)));
typedef float    floatx4 __attribute__((ext_vector_type(4)));

__global__ void k_init_deg(int* deg, int n) {
    int i = blockIdx.x * blockDim.x + threadIdx.x;
    if (i < n) deg[i] = 1;  // self-loop
}

__global__ void k_count(const int* __restrict__ dst, int* deg, int e) {
    int i = blockIdx.x * blockDim.x + threadIdx.x;
    if (i < e) atomicAdd(&deg[dst[i]], 1);
}

__global__ __launch_bounds__(SCAN_B) void k_scan1(const int* __restrict__ deg,
                                                  int* __restrict__ row_ptr,
                                                  int* __restrict__ bsum, int n) {
    __shared__ int tmp[SCAN_B];
    int tid = threadIdx.x;
    int i = blockIdx.x * SCAN_B + tid;
    int c = (i < n) ? (deg[i] - 1) : 0;
    tmp[tid] = c;
    __syncthreads();
    #pragma unroll
    for (int off = 1; off < SCAN_B; off <<= 1) {
        int v = (tid >= off) ? tmp[tid - off] : 0;
        __syncthreads();
        tmp[tid] += v;
        __syncthreads();
    }
    if (i < n) row_ptr[i] = tmp[tid] - c;
    if (tid == SCAN_B - 1) bsum[blockIdx.x] = tmp[tid];
}

__global__ __launch_bounds__(SCAN_B) void k_scan2(int* __restrict__ bsum, int nb) {
    __shared__ int tmp[SCAN_B];
    int tid = threadIdx.x;
    int c = (tid < nb) ? bsum[tid] : 0;
    tmp[tid] = c;
    __syncthreads();
    #pragma unroll
    for (int off = 1; off < SCAN_B; off <<= 1) {
        int v = (tid >= off) ? tmp[tid - off] : 0;
        __syncthreads();
        tmp[tid] += v;
        __syncthreads();
    }
    if (tid < nb) bsum[tid] = tmp[tid] - c;
}

__global__ __launch_bounds__(SCAN_B) void k_scan3(int* __restrict__ row_ptr,
                                                  const int* __restrict__ bsum,
                                                  int* __restrict__ cursor,
                                                  const int* __restrict__ deg,
                                                  float* __restrict__ dinv,
                                                  int n, int e) {
    int i = blockIdx.x * SCAN_B + threadIdx.x;
    if (i < n) {
        int r = row_ptr[i] + bsum[blockIdx.x];
        row_ptr[i] = r;
        cursor[i] = r;
        dinv[i] = rsqrtf((float)deg[i]);
    }
    if (i == 0) row_ptr[n] = e;
}

__global__ void k_fill(const int* __restrict__ src, const int* __restrict__ dst,
                       int* cursor, int* col, int e) {
    int i = blockIdx.x * blockDim.x + threadIdx.x;
    if (i < e) {
        int p = atomicAdd(&cursor[dst[i]], 1);
        col[p] = src[i];
    }
}

// Swizzle W[K][128] fp32 -> Bsw in MFMA B-fragment order, fp16.
// Bsw[((c*8+t)*64 + lane)*8 + j] = W[kmap(c*32 + (lane>>4)*8 + j)][t*16 + (lane&15)]
// permK: kmap = pi (for W2, whose K dim is the permuted h1 storage order).
__global__ void k_wswz(const float* __restrict__ W, _Float16* __restrict__ Bsw,
                       int K, int permK) {
    int o = blockIdx.x * blockDim.x + threadIdx.x;
    if (o >= K * 128) return;
    int j    = o & 7;
    int lane = (o >> 3) & 63;
    int t    = (o >> 9) & 7;
    int c    = o >> 12;
    int k = c * 32 + ((lane >> 4) << 3) + j;
    if (permK) k = ((k & 7) << 4) + (k >> 3);
    int ncol = t * 16 + (lane & 15);
    Bsw[o] = (_Float16)W[k * 128 + ncol];
}

// bp[p] = b[pi(p)]
__global__ void k_bperm(const float* __restrict__ b, float* __restrict__ bp) {
    int p = threadIdx.x;
    if (p < 128) bp[p] = b[((p & 7) << 4) + (p >> 3)];
}

// Cb[n,128](fp16, pi-permuted cols) = dinv[row] * (A[n,K] @ W[K,128]).
// Block: 256 thr = 4 waves, each wave a 16-row slab; 8 n-tiles; no LDS.
template<bool A32>
__global__ __launch_bounds__(256) void k_gemm_mfma(const void* __restrict__ Av,
                                                   const _Float16* __restrict__ Bsw,
                                                   _Float16* __restrict__ Cb,
                                                   const float* __restrict__ dinv,
                                                   int n, int K) {
    int tid   = threadIdx.x;
    int w     = tid >> 6;
    int ln    = tid & 63;
    int lane16 = ln & 15;
    int quad  = ln >> 4;
    int mrow  = blockIdx.x * 64 + w * 16 + lane16;   // A row this lane loads
    int mload = mrow < n ? mrow : n - 1;
    int nchunk = K >> 5;

    floatx4 acc[8];
    #pragma unroll
    for (int t = 0; t < 8; ++t) acc[t] = (floatx4){0.f, 0.f, 0.f, 0.f};

    for (int c = 0; c < nchunk; ++c) {
        half8 a;
        if constexpr (A32) {
            const float* ap = (const float*)Av + (size_t)mload * K + c * 32 + quad * 8;
            float4 v0 = *(const float4*)ap;
            float4 v1 = *(const float4*)(ap + 4);
            a[0] = (_Float16)v0.x; a[1] = (_Float16)v0.y;
            a[2] = (_Float16)v0.z; a[3] = (_Float16)v0.w;
            a[4] = (_Float16)v1.x; a[5] = (_Float16)v1.y;
            a[6] = (_Float16)v1.z; a[7] = (_Float16)v1.w;
        } else {
            const _Float16* ap = (const _Float16*)Av + (size_t)mload * K + c * 32 + quad * 8;
            a = *(const half8*)ap;
        }
        const _Float16* bp = Bsw + ((size_t)(c * 8) * 64 + ln) * 8;
        #pragma unroll
        for (int t = 0; t < 8; ++t) {
            half8 b = *(const half8*)(bp + (size_t)t * 512);
            acc[t] = __builtin_amdgcn_mfma_f32_16x16x32_f16(a, b, acc[t], 0, 0, 0);
        }
    }

    // D: row = quad*4+r, col = lane16 (per tile t). Store position p = lane16*8+t.
    int rbase = blockIdx.x * 64 + w * 16 + quad * 4;
    #pragma unroll
    for (int r = 0; r < 4; ++r) {
        int R = rbase + r;
        if (R < n) {
            float d = dinv[R];
            half8 o;
            #pragma unroll
            for (int t = 0; t < 8; ++t) o[t] = (_Float16)(acc[t][r] * d);
            *(half8*)(Cb + (size_t)R * 128 + lane16 * 8) = o;
        }
    }
}

// One wave per node; xwb rows prescaled by dinv[src], pi-permuted cols.
// OUT16: write fp16 (same permuted order). else: fp32, un-permuted (h2 -> d_out).
template<bool OUT16>
__global__ __launch_bounds__(256) void k_agg(const _Float16* __restrict__ xwb,
                                             const float* __restrict__ dinv,
                                             const int* __restrict__ row_ptr,
                                             const int* __restrict__ col,
                                             const float* __restrict__ bp,
                                             void* __restrict__ hout, int n) {
    int wave = threadIdx.x >> 6;
    int ln = threadIdx.x & 63;
    int i = blockIdx.x * 4 + wave;
    if (i >= n) return;
    int e0 = row_ptr[i], e1 = row_ptr[i + 1];
    float ax = 0.f, ay = 0.f;
    int e = e0;
    for (; e + 8 <= e1; e += 8) {
        int s0 = col[e + 0], s1 = col[e + 1], s2 = col[e + 2], s3 = col[e + 3];
        int s4 = col[e + 4], s5 = col[e + 5], s6 = col[e + 6], s7 = col[e + 7];
        half2v u0 = *(const half2v*)(xwb + (size_t)s0 * 128 + ln * 2);
        half2v u1 = *(const half2v*)(xwb + (size_t)s1 * 128 + ln * 2);
        half2v u2 = *(const half2v*)(xwb + (size_t)s2 * 128 + ln * 2);
        half2v u3 = *(const half2v*)(xwb + (size_t)s3 * 128 + ln * 2);
        half2v u4 = *(const half2v*)(xwb + (size_t)s4 * 128 + ln * 2);
        half2v u5 = *(const half2v*)(xwb + (size_t)s5 * 128 + ln * 2);
        half2v u6 = *(const half2v*)(xwb + (size_t)s6 * 128 + ln * 2);
        half2v u7 = *(const half2v*)(xwb + (size_t)s7 * 128 + ln * 2);
        ax += (float)u0[0] + (float)u1[0] + (float)u2[0] + (float)u3[0]
            + (float)u4[0] + (float)u5[0] + (float)u6[0] + (float)u7[0];
        ay += (float)u0[1] + (float)u1[1] + (float)u2[1] + (float)u3[1]
            + (float)u4[1] + (float)u5[1] + (float)u6[1] + (float)u7[1];
    }
    for (; e < e1; ++e) {
        int s = col[e];
        half2v u = *(const half2v*)(xwb + (size_t)s * 128 + ln * 2);
        ax += (float)u[0];
        ay += (float)u[1];
    }
    {   // self-loop
        half2v u = *(const half2v*)(xwb + (size_t)i * 128 + ln * 2);
        ax += (float)u[0];
        ay += (float)u[1];
    }
    float di = dinv[i];
    float2 b = *(const float2*)(bp + ln * 2);
    float ox = fmaxf(fmaf(di, ax, b.x), 0.f);
    float oy = fmaxf(fmaf(di, ay, b.y), 0.f);
    if constexpr (OUT16) {
        half2v o; o[0] = (_Float16)ox; o[1] = (_Float16)oy;
        *(half2v*)((_Float16*)hout + (size_t)i * 128 + ln * 2) = o;
    } else {
        float* hf = (float*)hout;
        int p0 = 2 * ln, p1 = 2 * ln + 1;
        int c0 = ((p0 & 7) << 4) + (p0 >> 3);
        int c1 = ((p1 & 7) << 4) + (p1 >> 3);
        hf[(size_t)i * 128 + c0] = ox;
        hf[(size_t)i * 128 + c1] = oy;
    }
}

// out[n,16] = h2[n,128] @ Wc[128,16] + bc. (h2 fp32, un-permuted.)
__global__ __launch_bounds__(256) void k_out(const float* __restrict__ h2,
                                             const float* __restrict__ Wc,
                                             const float* __restrict__ bc,
                                             float* __restrict__ out, int n) {
    __shared__ float Ws[128 * 16];
    __shared__ float bs[16];
    __shared__ float hs[16][128];
    int tid = threadIdx.x;
    for (int t = tid; t < 128 * 16; t += 256) Ws[t] = Wc[t];
    if (tid < 16) bs[tid] = bc[tid];
    int r0 = blockIdx.x * 16;
    {
        int r = tid >> 4;
        int c = (tid & 15) * 8;
        int row = r0 + r;
        if (row < n) {
            const float* hp = h2 + (size_t)row * 128 + c;
            *(float4*)&hs[r][c]     = *(const float4*)hp;
            *(float4*)&hs[r][c + 4] = *(const float4*)(hp + 4);
        }
    }
    __syncthreads();
    int ti = tid >> 4, j = tid & 15;
    float acc = bs[j];
    #pragma unroll 8
    for (int k = 0; k < 128; ++k) acc = fmaf(hs[ti][k], Ws[k * 16 + j], acc);
    int row = r0 + ti;
    if (row < n) out[(size_t)row * 16 + j] = acc;
}

static inline size_t align256(size_t x) { return (x + 255) & ~(size_t)255; }

extern "C" void kernel_launch(void* const* d_in, const int* in_sizes, int n_in,
                              void* d_out, int out_size, void* d_ws, size_t ws_size,
                              hipStream_t stream) {
    const float* fts = (const float*)d_in[0];
    const int*   ei  = (const int*)d_in[1];
    const float* W1  = (const float*)d_in[2];
    const float* b1  = (const float*)d_in[3];
    const float* W2  = (const float*)d_in[4];
    const float* b2  = (const float*)d_in[5];
    const float* Wc  = (const float*)d_in[6];
    const float* bc  = (const float*)d_in[7];

    const int N = in_sizes[0] / IN_DIM;     // 50000
    const int E = in_sizes[1] / 2;          // 800000
    const int* src = ei;
    const int* dst = ei + E;

    char* p = (char*)d_ws;
    int* deg      = (int*)p;               p += align256(sizeof(int) * N);
    int* row_ptr  = (int*)p;               p += align256(sizeof(int) * (N + 1));
    int* cursor   = (int*)p;               p += align256(sizeof(int) * N);
    float* dinv   = (float*)p;             p += align256(sizeof(float) * N);
    int* col      = (int*)p;               p += align256(sizeof(int) * E);
    int* bsum     = (int*)p;               p += align256(sizeof(int) * 512);
    _Float16* Bsw1 = (_Float16*)p;         p += align256(sizeof(_Float16) * IN_DIM * HID);
    _Float16* Bsw2 = (_Float16*)p;         p += align256(sizeof(_Float16) * HID * HID);
    float* bp1    = (float*)p;             p += align256(sizeof(float) * HID);
    float* bp2    = (float*)p;             p += align256(sizeof(float) * HID);
    _Float16* xwb = (_Float16*)p;          p += align256(sizeof(_Float16) * (size_t)N * HID);
    _Float16* h1  = (_Float16*)p;          p += align256(sizeof(_Float16) * (size_t)N * HID);

    float* out = (float*)d_out;                   // [N,16]
    float* h2  = (float*)d_out + (size_t)N * 16;  // [N,128]

    const int T = 256;
    dim3 gN((N + T - 1) / T), gE((E + T - 1) / T);
    const int nScanB = (N + SCAN_B - 1) / SCAN_B;

    // Graph structure
    k_init_deg<<<gN, T, 0, stream>>>(deg, N);
    k_count<<<gE, T, 0, stream>>>(dst, deg, E);
    k_scan1<<<nScanB, SCAN_B, 0, stream>>>(deg, row_ptr, bsum, N);
    k_scan2<<<1, SCAN_B, 0, stream>>>(bsum, nScanB);
    k_scan3<<<nScanB, SCAN_B, 0, stream>>>(row_ptr, bsum, cursor, deg, dinv, N, E);
    k_fill<<<gE, T, 0, stream>>>(src, dst, cursor, col, E);

    // Weight/bias prep
    k_wswz<<<(IN_DIM * HID + 255) / 256, T, 0, stream>>>(W1, Bsw1, IN_DIM, 0);
    k_wswz<<<(HID * HID + 255) / 256, T, 0, stream>>>(W2, Bsw2, HID, 1);
    k_bperm<<<1, 128, 0, stream>>>(b1, bp1);
    k_bperm<<<1, 128, 0, stream>>>(b2, bp2);

    dim3 gGemm((N + 63) / 64);
    dim3 gAgg((N + 3) / 4);

    // Layer 1
    k_gemm_mfma<true><<<gGemm, T, 0, stream>>>(fts, Bsw1, xwb, dinv, N, IN_DIM);
    k_agg<true><<<gAgg, T, 0, stream>>>(xwb, dinv, row_ptr, col, bp1, h1, N);
    // Layer 2
    k_gemm_mfma<false><<<gGemm, T, 0, stream>>>(h1, Bsw2, xwb, dinv, N, HID);
    k_agg<false><<<gAgg, T, 0, stream>>>(xwb, dinv, row_ptr, col, bp2, h2, N);
    // Classifier
    k_out<<<(N + 15) / 16, T, 0, stream>>>(h2, Wc, bc, out, N);
}

// Round 6
// 289.134 us; speedup vs baseline: 1.9054x; 1.1412x over previous
//
#include <hip/hip_runtime.h>

// ---------------------------------------------------------------------------
// GCN: x1 = relu(Ahat @ (fts@W1) + b1); x2 = relu(Ahat @ (x1@W2) + b2);
//      out = x2@Wc + bc.  Ahat = D^-1/2 (A + I) D^-1/2.
// d_out = [out (N*16) | x2 (N*128)] fp32.
// R2: hierarchical scan. R3: gather prescale+unroll. R4: MFMA fp16 GEMMs.
// R5: slot-capture CSR build (atomic-free k_fill).
// R6: FIX R5 crash — deg must start at 0 so slot starts at 0 (R5 seeded
//     deg=1 -> col[row_ptr[i]] left 0xAA-poisoned -> wild gather -> abort).
//     Self-loop folded in via dinv = rsqrt(deg+1); scan runs over deg itself.
// ---------------------------------------------------------------------------

#define IN_DIM 256
#define HID 128
#define OUT_DIM 16
#define SCAN_B 256

typedef _Float16 half8  __attribute__((ext_vector_type(8)));
typedef _Float16 half2v __attribute__((ext_vector_type(2)));
typedef float    floatx4 __attribute__((ext_vector_type(4)));

__global__ void k_init_deg(int* deg, int n) {
    int i = blockIdx.x * blockDim.x + threadIdx.x;
    if (i < n) deg[i] = 0;   // EDGE count only; self-loop added in dinv
}

// slot[i] = old count — the edge's slot within its dst row (0-based). int4.
__global__ void k_count(const int* __restrict__ dst, int* deg,
                        int* __restrict__ slot, int e4, int e) {
    int i = blockIdx.x * blockDim.x + threadIdx.x;
    if (i < e4) {
        int4 d = ((const int4*)dst)[i];
        int4 s;
        s.x = atomicAdd(&deg[d.x], 1);
        s.y = atomicAdd(&deg[d.y], 1);
        s.z = atomicAdd(&deg[d.z], 1);
        s.w = atomicAdd(&deg[d.w], 1);
        ((int4*)slot)[i] = s;
    }
    int base = e4 * 4;
    int t = blockIdx.x * blockDim.x + threadIdx.x;
    if (t < e - base) {  // tail
        slot[base + t] = atomicAdd(&deg[dst[base + t]], 1);
    }
}

__global__ __launch_bounds__(SCAN_B) void k_scan1(const int* __restrict__ deg,
                                                  int* __restrict__ row_ptr,
                                                  int* __restrict__ bsum, int n) {
    __shared__ int tmp[SCAN_B];
    int tid = threadIdx.x;
    int i = blockIdx.x * SCAN_B + tid;
    int c = (i < n) ? deg[i] : 0;
    tmp[tid] = c;
    __syncthreads();
    #pragma unroll
    for (int off = 1; off < SCAN_B; off <<= 1) {
        int v = (tid >= off) ? tmp[tid - off] : 0;
        __syncthreads();
        tmp[tid] += v;
        __syncthreads();
    }
    if (i < n) row_ptr[i] = tmp[tid] - c;
    if (tid == SCAN_B - 1) bsum[blockIdx.x] = tmp[tid];
}

__global__ __launch_bounds__(SCAN_B) void k_scan2(int* __restrict__ bsum, int nb) {
    __shared__ int tmp[SCAN_B];
    int tid = threadIdx.x;
    int c = (tid < nb) ? bsum[tid] : 0;
    tmp[tid] = c;
    __syncthreads();
    #pragma unroll
    for (int off = 1; off < SCAN_B; off <<= 1) {
        int v = (tid >= off) ? tmp[tid - off] : 0;
        __syncthreads();
        tmp[tid] += v;
        __syncthreads();
    }
    if (tid < nb) bsum[tid] = tmp[tid] - c;
}

__global__ __launch_bounds__(SCAN_B) void k_scan3(int* __restrict__ row_ptr,
                                                  const int* __restrict__ bsum,
                                                  const int* __restrict__ deg,
                                                  float* __restrict__ dinv,
                                                  int n, int e) {
    int i = blockIdx.x * SCAN_B + threadIdx.x;
    if (i < n) {
        row_ptr[i] += bsum[blockIdx.x];
        dinv[i] = rsqrtf((float)(deg[i] + 1));   // +1 self-loop
    }
    if (i == 0) row_ptr[n] = e;
}

// Atomic-free scatter: col[row_ptr[dst]+slot] = src. int4-vectorized.
__global__ void k_fill(const int* __restrict__ src, const int* __restrict__ dst,
                       const int* __restrict__ slot, const int* __restrict__ row_ptr,
                       int* __restrict__ col, int e4, int e) {
    int i = blockIdx.x * blockDim.x + threadIdx.x;
    if (i < e4) {
        int4 sv = ((const int4*)src)[i];
        int4 dv = ((const int4*)dst)[i];
        int4 sl = ((const int4*)slot)[i];
        col[row_ptr[dv.x] + sl.x] = sv.x;
        col[row_ptr[dv.y] + sl.y] = sv.y;
        col[row_ptr[dv.z] + sl.z] = sv.z;
        col[row_ptr[dv.w] + sl.w] = sv.w;
    }
    int base = e4 * 4;
    int t = blockIdx.x * blockDim.x + threadIdx.x;
    if (t < e - base) {
        int j = base + t;
        col[row_ptr[dst[j]] + slot[j]] = src[j];
    }
}

// Swizzle W[K][128] fp32 -> Bsw in MFMA B-fragment order, fp16.
__global__ void k_wswz(const float* __restrict__ W, _Float16* __restrict__ Bsw,
                       int K, int permK) {
    int o = blockIdx.x * blockDim.x + threadIdx.x;
    if (o >= K * 128) return;
    int j    = o & 7;
    int lane = (o >> 3) & 63;
    int t    = (o >> 9) & 7;
    int c    = o >> 12;
    int k = c * 32 + ((lane >> 4) << 3) + j;
    if (permK) k = ((k & 7) << 4) + (k >> 3);
    int ncol = t * 16 + (lane & 15);
    Bsw[o] = (_Float16)W[k * 128 + ncol];
}

// bp[p] = b[pi(p)]
__global__ void k_bperm(const float* __restrict__ b, float* __restrict__ bp) {
    int p = threadIdx.x;
    if (p < 128) bp[p] = b[((p & 7) << 4) + (p >> 3)];
}

// Cb[n,128](fp16, pi-permuted cols) = dinv[row] * (A[n,K] @ W[K,128]).
template<bool A32>
__global__ __launch_bounds__(256) void k_gemm_mfma(const void* __restrict__ Av,
                                                   const _Float16* __restrict__ Bsw,
                                                   _Float16* __restrict__ Cb,
                                                   const float* __restrict__ dinv,
                                                   int n, int K) {
    int tid   = threadIdx.x;
    int w     = tid >> 6;
    int ln    = tid & 63;
    int lane16 = ln & 15;
    int quad  = ln >> 4;
    int mrow  = blockIdx.x * 64 + w * 16 + lane16;
    int mload = mrow < n ? mrow : n - 1;
    int nchunk = K >> 5;

    floatx4 acc[8];
    #pragma unroll
    for (int t = 0; t < 8; ++t) acc[t] = (floatx4){0.f, 0.f, 0.f, 0.f};

    for (int c = 0; c < nchunk; ++c) {
        half8 a;
        if constexpr (A32) {
            const float* ap = (const float*)Av + (size_t)mload * K + c * 32 + quad * 8;
            float4 v0 = *(const float4*)ap;
            float4 v1 = *(const float4*)(ap + 4);
            a[0] = (_Float16)v0.x; a[1] = (_Float16)v0.y;
            a[2] = (_Float16)v0.z; a[3] = (_Float16)v0.w;
            a[4] = (_Float16)v1.x; a[5] = (_Float16)v1.y;
            a[6] = (_Float16)v1.z; a[7] = (_Float16)v1.w;
        } else {
            const _Float16* ap = (const _Float16*)Av + (size_t)mload * K + c * 32 + quad * 8;
            a = *(const half8*)ap;
        }
        const _Float16* bp = Bsw + ((size_t)(c * 8) * 64 + ln) * 8;
        #pragma unroll
        for (int t = 0; t < 8; ++t) {
            half8 b = *(const half8*)(bp + (size_t)t * 512);
            acc[t] = __builtin_amdgcn_mfma_f32_16x16x32_f16(a, b, acc[t], 0, 0, 0);
        }
    }

    int rbase = blockIdx.x * 64 + w * 16 + quad * 4;
    #pragma unroll
    for (int r = 0; r < 4; ++r) {
        int R = rbase + r;
        if (R < n) {
            float d = dinv[R];
            half8 o;
            #pragma unroll
            for (int t = 0; t < 8; ++t) o[t] = (_Float16)(acc[t][r] * d);
            *(half8*)(Cb + (size_t)R * 128 + lane16 * 8) = o;
        }
    }
}

// One wave per node; xwb rows prescaled by dinv[src], pi-permuted cols.
template<bool OUT16>
__global__ __launch_bounds__(256) void k_agg(const _Float16* __restrict__ xwb,
                                             const float* __restrict__ dinv,
                                             const int* __restrict__ row_ptr,
                                             const int* __restrict__ col,
                                             const float* __restrict__ bp,
                                             void* __restrict__ hout, int n) {
    int wave = threadIdx.x >> 6;
    int ln = threadIdx.x & 63;
    int i = blockIdx.x * 4 + wave;
    if (i >= n) return;
    int e0 = row_ptr[i], e1 = row_ptr[i + 1];
    float ax = 0.f, ay = 0.f;
    int e = e0;
    for (; e + 8 <= e1; e += 8) {
        int s0 = col[e + 0], s1 = col[e + 1], s2 = col[e + 2], s3 = col[e + 3];
        int s4 = col[e + 4], s5 = col[e + 5], s6 = col[e + 6], s7 = col[e + 7];
        half2v u0 = *(const half2v*)(xwb + (size_t)s0 * 128 + ln * 2);
        half2v u1 = *(const half2v*)(xwb + (size_t)s1 * 128 + ln * 2);
        half2v u2 = *(const half2v*)(xwb + (size_t)s2 * 128 + ln * 2);
        half2v u3 = *(const half2v*)(xwb + (size_t)s3 * 128 + ln * 2);
        half2v u4 = *(const half2v*)(xwb + (size_t)s4 * 128 + ln * 2);
        half2v u5 = *(const half2v*)(xwb + (size_t)s5 * 128 + ln * 2);
        half2v u6 = *(const half2v*)(xwb + (size_t)s6 * 128 + ln * 2);
        half2v u7 = *(const half2v*)(xwb + (size_t)s7 * 128 + ln * 2);
        ax += (float)u0[0] + (float)u1[0] + (float)u2[0] + (float)u3[0]
            + (float)u4[0] + (float)u5[0] + (float)u6[0] + (float)u7[0];
        ay += (float)u0[1] + (float)u1[1] + (float)u2[1] + (float)u3[1]
            + (float)u4[1] + (float)u5[1] + (float)u6[1] + (float)u7[1];
    }
    for (; e < e1; ++e) {
        int s = col[e];
        half2v u = *(const half2v*)(xwb + (size_t)s * 128 + ln * 2);
        ax += (float)u[0];
        ay += (float)u[1];
    }
    {   // self-loop
        half2v u = *(const half2v*)(xwb + (size_t)i * 128 + ln * 2);
        ax += (float)u[0];
        ay += (float)u[1];
    }
    float di = dinv[i];
    float2 b = *(const float2*)(bp + ln * 2);
    float ox = fmaxf(fmaf(di, ax, b.x), 0.f);
    float oy = fmaxf(fmaf(di, ay, b.y), 0.f);
    if constexpr (OUT16) {
        half2v o; o[0] = (_Float16)ox; o[1] = (_Float16)oy;
        *(half2v*)((_Float16*)hout + (size_t)i * 128 + ln * 2) = o;
    } else {
        float* hf = (float*)hout;
        int p0 = 2 * ln, p1 = 2 * ln + 1;
        int c0 = ((p0 & 7) << 4) + (p0 >> 3);
        int c1 = ((p1 & 7) << 4) + (p1 >> 3);
        hf[(size_t)i * 128 + c0] = ox;
        hf[(size_t)i * 128 + c1] = oy;
    }
}

// out[n,16] = h2[n,128] @ Wc[128,16] + bc. (h2 fp32, un-permuted.)
__global__ __launch_bounds__(256) void k_out(const float* __restrict__ h2,
                                             const float* __restrict__ Wc,
                                             const float* __restrict__ bc,
                                             float* __restrict__ out, int n) {
    __shared__ float Ws[128 * 16];
    __shared__ float bs[16];
    __shared__ float hs[16][128];
    int tid = threadIdx.x;
    for (int t = tid; t < 128 * 16; t += 256) Ws[t] = Wc[t];
    if (tid < 16) bs[tid] = bc[tid];
    int r0 = blockIdx.x * 16;
    {
        int r = tid >> 4;
        int c = (tid & 15) * 8;
        int row = r0 + r;
        if (row < n) {
            const float* hp = h2 + (size_t)row * 128 + c;
            *(float4*)&hs[r][c]     = *(const float4*)hp;
            *(float4*)&hs[r][c + 4] = *(const float4*)(hp + 4);
        }
    }
    __syncthreads();
    int ti = tid >> 4, j = tid & 15;
    float acc = bs[j];
    #pragma unroll 8
    for (int k = 0; k < 128; ++k) acc = fmaf(hs[ti][k], Ws[k * 16 + j], acc);
    int row = r0 + ti;
    if (row < n) out[(size_t)row * 16 + j] = acc;
}

static inline size_t align256(size_t x) { return (x + 255) & ~(size_t)255; }

extern "C" void kernel_launch(void* const* d_in, const int* in_sizes, int n_in,
                              void* d_out, int out_size, void* d_ws, size_t ws_size,
                              hipStream_t stream) {
    const float* fts = (const float*)d_in[0];
    const int*   ei  = (const int*)d_in[1];
    const float* W1  = (const float*)d_in[2];
    const float* b1  = (const float*)d_in[3];
    const float* W2  = (const float*)d_in[4];
    const float* b2  = (const float*)d_in[5];
    const float* Wc  = (const float*)d_in[6];
    const float* bc  = (const float*)d_in[7];

    const int N = in_sizes[0] / IN_DIM;     // 50000
    const int E = in_sizes[1] / 2;          // 800000
    const int* src = ei;
    const int* dst = ei + E;

    char* p = (char*)d_ws;
    int* deg      = (int*)p;               p += align256(sizeof(int) * N);
    int* row_ptr  = (int*)p;               p += align256(sizeof(int) * (N + 1));
    float* dinv   = (float*)p;             p += align256(sizeof(float) * N);
    int* slot     = (int*)p;               p += align256(sizeof(int) * E);
    int* col      = (int*)p;               p += align256(sizeof(int) * E);
    int* bsum     = (int*)p;               p += align256(sizeof(int) * 512);
    _Float16* Bsw1 = (_Float16*)p;         p += align256(sizeof(_Float16) * IN_DIM * HID);
    _Float16* Bsw2 = (_Float16*)p;         p += align256(sizeof(_Float16) * HID * HID);
    float* bp1    = (float*)p;             p += align256(sizeof(float) * HID);
    float* bp2    = (float*)p;             p += align256(sizeof(float) * HID);
    _Float16* xwb = (_Float16*)p;          p += align256(sizeof(_Float16) * (size_t)N * HID);
    _Float16* h1  = (_Float16*)p;          p += align256(sizeof(_Float16) * (size_t)N * HID);

    float* out = (float*)d_out;                   // [N,16]
    float* h2  = (float*)d_out + (size_t)N * 16;  // [N,128]

    const int T = 256;
    dim3 gN((N + T - 1) / T);
    const int E4 = E / 4;
    dim3 gE4((E4 + T - 1) / T);
    const int nScanB = (N + SCAN_B - 1) / SCAN_B;

    // Graph structure
    k_init_deg<<<gN, T, 0, stream>>>(deg, N);
    k_count<<<gE4, T, 0, stream>>>(dst, deg, slot, E4, E);
    k_scan1<<<nScanB, SCAN_B, 0, stream>>>(deg, row_ptr, bsum, N);
    k_scan2<<<1, SCAN_B, 0, stream>>>(bsum, nScanB);
    k_scan3<<<nScanB, SCAN_B, 0, stream>>>(row_ptr, bsum, deg, dinv, N, E);
    k_fill<<<gE4, T, 0, stream>>>(src, dst, slot, row_ptr, col, E4, E);

    // Weight/bias prep
    k_wswz<<<(IN_DIM * HID + 255) / 256, T, 0, stream>>>(W1, Bsw1, IN_DIM, 0);
    k_wswz<<<(HID * HID + 255) / 256, T, 0, stream>>>(W2, Bsw2, HID, 1);
    k_bperm<<<1, 128, 0, stream>>>(b1, bp1);
    k_bperm<<<1, 128, 0, stream>>>(b2, bp2);

    dim3 gGemm((N + 63) / 64);
    dim3 gAgg((N + 3) / 4);

    // Layer 1
    k_gemm_mfma<true><<<gGemm, T, 0, stream>>>(fts, Bsw1, xwb, dinv, N, IN_DIM);
    k_agg<true><<<gAgg, T, 0, stream>>>(xwb, dinv, row_ptr, col, bp1, h1, N);
    // Layer 2
    k_gemm_mfma<false><<<gGemm, T, 0, stream>>>(h1, Bsw2, xwb, dinv, N, HID);
    k_agg<false><<<gAgg, T, 0, stream>>>(xwb, dinv, row_ptr, col, bp2, h2, N);
    // Classifier
    k_out<<<(N + 15) / 16, T, 0, stream>>>(h2, Wc, bc, out, N);
}